// Round 16
// baseline (89.406 us; speedup 1.0000x reference)
//
#include <hip/hip_runtime.h>
#include <stdint.h>

typedef _Float16 f16x8 __attribute__((ext_vector_type(8)));
typedef __fp16 fp16x2 __attribute__((ext_vector_type(2)));
typedef float f32x4 __attribute__((ext_vector_type(4)));

#define BC (16384 * 256)

__device__ __forceinline__ f16x8 cvt8(f32x4 a, f32x4 b) {
  fp16x2 p0 = __builtin_amdgcn_cvt_pkrtz(a[0], a[1]);
  fp16x2 p1 = __builtin_amdgcn_cvt_pkrtz(a[2], a[3]);
  fp16x2 p2 = __builtin_amdgcn_cvt_pkrtz(b[0], b[1]);
  fp16x2 p3 = __builtin_amdgcn_cvt_pkrtz(b[2], b[3]);
  f16x8 o;
  o[0] = (_Float16)p0[0]; o[1] = (_Float16)p0[1];
  o[2] = (_Float16)p1[0]; o[3] = (_Float16)p1[1];
  o[4] = (_Float16)p2[0]; o[5] = (_Float16)p2[1];
  o[6] = (_Float16)p3[0]; o[7] = (_Float16)p3[1];
  return o;
}

__device__ __forceinline__ float tanh_fast(float v) {
  float a = fminf(fabsf(v), 18.f);
  float t = __expf(2.f * a);
  float r = (t - 1.f) * __builtin_amdgcn_rcpf(t + 1.f);
  return copysignf(r, v);
}

// Pack Wu/Wg/Wa/Wd -> wsB f16 at 64-packed-col granularity, kt-outermost per
// cbh, BK=32 swizzle baked in:
// tid = ((cbh*16 + kt)*64 + pr)*4 + slot; writes 8 f16 at wsB + tid*8, holding
//   W_s[c][k] with s = pr>>4, c = cbh*16 + (pr&15),
//   k = kt*32 + (slot ^ ((pr>>1)&3))*8 + b.
// Per (cbh,kt) slab: 64 pr x 4 slots x 16 B = 4 KB contiguous (4 glds rounds).
// strip s=0 is Wu (k >= 256 zero-padded).
__global__ __launch_bounds__(256) void pack_w(const float* __restrict__ Wu,
                                              const float* __restrict__ Wg,
                                              const float* __restrict__ Wa,
                                              const float* __restrict__ Wd,
                                              _Float16* __restrict__ wsB) {
  int tid = blockIdx.x * 256 + threadIdx.x;  // 65536 total
  int slot = tid & 3;
  int pr = (tid >> 2) & 63;
  int kt = (tid >> 8) & 15;
  int cbh = tid >> 12;  // 0..15
  int s = pr >> 4;
  int c = cbh * 16 + (pr & 15);
  int k0 = kt * 32 + (slot ^ ((pr >> 1) & 3)) * 8;
  float v[8];
  if (s == 0) {
    if (k0 < 256) {
      const float* p = Wu + (size_t)c * 256 + k0;
#pragma unroll
      for (int i = 0; i < 8; ++i) v[i] = p[i];
    } else {
#pragma unroll
      for (int i = 0; i < 8; ++i) v[i] = 0.f;
    }
  } else {
    const float* p = (s == 1 ? Wg : (s == 2 ? Wa : Wd)) + (size_t)c * 512 + k0;
#pragma unroll
    for (int i = 0; i < 8; ++i) v[i] = p[i];
  }
  f32x4 a = {v[0], v[1], v[2], v[3]};
  f32x4 b = {v[4], v[5], v[6], v[7]};
  *reinterpret_cast<f16x8*>(wsB + (size_t)tid * 8) = cvt8(a, b);
}

// Wave-autonomous fused GEMM + epilogue: 1-wave blocks, ZERO s_barrier.
// Wave tile: 32 rows x 64 packed cols (4 strips x 16 c). A: direct per-lane
// f32 loads -> cvt_pkrtz -> regs (no LDS). B: glds into private 8 KB LDS
// double-buffer, counted vmcnt (same-wave visibility). All waits wave-local.
__global__ __launch_bounds__(64, 4) void rwa_main(
    const float* __restrict__ x, const float* __restrict__ nt_,
    const float* __restrict__ dt_, const float* __restrict__ h,
    const float* __restrict__ amax_, const float* __restrict__ bu,
    const float* __restrict__ bg, const _Float16* __restrict__ wsB,
    float* __restrict__ out) {
  __shared__ __align__(16) _Float16 ldsB[2][64 * 32];  // 2 x 4 KB, private

  const int lane = threadIdx.x;  // 0..63
  const int l15 = lane & 15;
  const int lg = lane >> 4;

  // XCD swizzle: per XCD, cbh fastest -> A stripe (16 consecutive blocks share
  // it) and that cbh's 64 KB weight slab stay L2-hot.
  const int bid = blockIdx.x;  // 0..8191
  const int xcd = bid & 7;
  const int q = bid >> 3;           // 0..1023
  const int cbh = q & 15;           // 16-wide c chunk
  const int r32 = xcd * 64 + (q >> 4);  // 0..511
  const int row0 = r32 * 32;

  // A direct-load bases: lane covers rows {row0 + mi*16 + l15}, k cols lg*8..+8.
  const float* xr0 = x + (size_t)(row0 + l15) * 256 + lg * 8;
  const float* hr0 = h + (size_t)(row0 + l15) * 256 + lg * 8;
  const float* xr1 = xr0 + 16 * 256;
  const float* hr1 = hr0 + 16 * 256;

  // B staging source: slab (cbh,kt) is 4 KB contiguous; lane copies 16 B x 4.
  const _Float16* bslab = wsB + (size_t)cbh * 32768 + (size_t)lane * 8;

  f32x4 acc[2][4] = {};  // [mi][strip]
  f32x4 a0, a1, a2, a3;  // in-flight A f32 (next tile): mi0 = a0,a1; mi1 = a2,a3

  auto issueA = [&](int kt) {
    const float* p0 = (kt < 8 ? xr0 : hr0) + (kt & 7) * 32;
    const float* p1 = (kt < 8 ? xr1 : hr1) + (kt & 7) * 32;
    a0 = *reinterpret_cast<const f32x4*>(p0);
    a1 = *reinterpret_cast<const f32x4*>(p0 + 4);
    a2 = *reinterpret_cast<const f32x4*>(p1);
    a3 = *reinterpret_cast<const f32x4*>(p1 + 4);
  };
  auto issueB = [&](int buf, int kt) {
#pragma unroll
    for (int i = 0; i < 4; ++i) {
      __builtin_amdgcn_global_load_lds(
          (const __attribute__((address_space(1))) uint32_t*)(bslab + (size_t)kt * 2048 + i * 512),
          (__attribute__((address_space(3))) uint32_t*)(&ldsB[buf][0] + i * 512),
          16, 0, 0);
    }
  };

  // Prologue: tile 0 in flight.
  issueA(0);
  issueB(0, 0);

#pragma unroll
  for (int kt = 0; kt < 16; ++kt) {
    const int buf = kt & 1;

    // Convert A(kt) (compiler inserts the vmcnt for a0..a3 arrival).
    f16x8 af0 = cvt8(a0, a1);
    f16x8 af1 = cvt8(a2, a3);

    // Issue next tile: A f32 loads (regs now free), B glds into other buffer.
    if (kt < 15) {
      issueA(kt + 1);
      issueB(buf ^ 1, kt + 1);
    }

    // Retire B(kt) only: 8 newest (A(kt+1) 4 + B(kt+1) 4) stay in flight.
    if (kt < 15) {
      asm volatile("s_waitcnt vmcnt(8)" ::: "memory");
    } else {
      asm volatile("s_waitcnt vmcnt(0)" ::: "memory");
    }
    __builtin_amdgcn_sched_barrier(0);

    // Compute tile kt from private LDS.
    const bool doU = (kt < 8);  // Wu strip zero-padded beyond k=256
    const char* pB = reinterpret_cast<const char*>(&ldsB[buf][0]);
    f16x8 bf[4];
#pragma unroll
    for (int s = 0; s < 4; ++s) {
      if (s == 0 && !doU) continue;
      const int pr = s * 16 + l15;
      bf[s] = *reinterpret_cast<const f16x8*>(pB + pr * 64 + ((lg ^ ((pr >> 1) & 3)) << 4));
    }
#pragma unroll
    for (int s = 0; s < 4; ++s) {
      if (s == 0 && !doU) continue;
      acc[0][s] = __builtin_amdgcn_mfma_f32_16x16x32_f16(af0, bf[s], acc[0][s], 0, 0, 0);
      acc[1][s] = __builtin_amdgcn_mfma_f32_16x16x32_f16(af1, bf[s], acc[1][s], 0, 0, 0);
    }
  }

  __builtin_amdgcn_sched_barrier(0);  // keep epilogue below the loop

  // Epilogue: lane owns (r,c); u,g,a,dec local. C/D: col=l15, row=lg*4+rg (+mi*16).
  const int c = cbh * 16 + l15;
  const float buv = bu[c];
  const float bgv = bg[c];
#pragma unroll
  for (int mi = 0; mi < 2; ++mi) {
#pragma unroll
    for (int rg = 0; rg < 4; ++rg) {
      const int r = row0 + mi * 16 + lg * 4 + rg;
      const int idx = r * 256 + c;
      const float u = acc[mi][0][rg] + buv;
      const float gt = acc[mi][1][rg] + bgv;
      const float a = acc[mi][2][rg];
      const float dr = acc[mi][3][rg];
      const float sig = __builtin_amdgcn_rcpf(1.f + __expf(-dr));
      const float z = u * tanh_fast(gt);
      const float am = amax_[idx];
      const float n_old = nt_[idx];
      const float d_old = dt_[idx];
      const float e_neg = __expf(-sig);
      const float a_new = fmaxf(am * e_neg, a);
      const float comm = __expf(am - a_new - sig);  // e_neg * exp(am - a_new)
      const float escal = __expf(a - a_new);
      const float n_new = n_old * comm + z * escal;
      const float d_new = d_old * comm + escal;
      const float h_new = tanh_fast(n_new * __builtin_amdgcn_rcpf(d_new));
      out[idx] = n_new;
      out[BC + idx] = d_new;
      out[2 * BC + idx] = h_new;
      out[3 * BC + idx] = a_new;
    }
  }
}

extern "C" void kernel_launch(void* const* d_in, const int* in_sizes, int n_in,
                              void* d_out, int out_size, void* d_ws, size_t ws_size,
                              hipStream_t stream) {
  const float* x_t    = (const float*)d_in[0];
  const float* n_t    = (const float*)d_in[1];
  const float* d_t    = (const float*)d_in[2];
  const float* h_t    = (const float*)d_in[3];
  const float* amax_t = (const float*)d_in[4];
  const float* Wu     = (const float*)d_in[5];
  const float* bu     = (const float*)d_in[6];
  const float* Wg     = (const float*)d_in[7];
  const float* bg     = (const float*)d_in[8];
  const float* Wa     = (const float*)d_in[9];
  const float* Wd     = (const float*)d_in[10];
  float* out = (float*)d_out;

  _Float16* wsB = (_Float16*)d_ws;  // 1 MB packed weights (64-pc granular)

  pack_w<<<256, 256, 0, stream>>>(Wu, Wg, Wa, Wd, wsB);
  rwa_main<<<8192, 64, 0, stream>>>(x_t, n_t, d_t, h_t, amax_t, bu, bg, wsB, out);
}

// Round 18
// 48.093 us; speedup vs baseline: 1.8590x; 1.8590x over previous
//
#include <hip/hip_runtime.h>
#include <stdint.h>

typedef _Float16 f16x8 __attribute__((ext_vector_type(8)));
typedef __fp16 fp16x2 __attribute__((ext_vector_type(2)));
typedef float f32x4 __attribute__((ext_vector_type(4)));

#define BC (16384 * 256)

__device__ __forceinline__ f16x8 cvt8(f32x4 a, f32x4 b) {
  fp16x2 p0 = __builtin_amdgcn_cvt_pkrtz(a[0], a[1]);
  fp16x2 p1 = __builtin_amdgcn_cvt_pkrtz(a[2], a[3]);
  fp16x2 p2 = __builtin_amdgcn_cvt_pkrtz(b[0], b[1]);
  fp16x2 p3 = __builtin_amdgcn_cvt_pkrtz(b[2], b[3]);
  f16x8 o;
  o[0] = (_Float16)p0[0]; o[1] = (_Float16)p0[1];
  o[2] = (_Float16)p1[0]; o[3] = (_Float16)p1[1];
  o[4] = (_Float16)p2[0]; o[5] = (_Float16)p2[1];
  o[6] = (_Float16)p3[0]; o[7] = (_Float16)p3[1];
  return o;
}

__device__ __forceinline__ float tanh_fast(float v) {
  float a = fminf(fabsf(v), 18.f);
  float t = __expf(2.f * a);
  float r = (t - 1.f) * __builtin_amdgcn_rcpf(t + 1.f);
  return copysignf(r, v);
}

// Pack Wu/Wg/Wa/Wd -> wsB f16, kt-outermost, BK=32 LDS swizzle baked in
// (R8/R14 layout, verified):
// elem = (((kt*8 + cb)*128 + row)*4 + slot)*8 + b, holding W_strip[c][k] with
//   row = wn*64 + strip*16 + t16, c = cb*32 + wn*16 + t16,
//   k = kt*32 + (slot ^ ((row>>1)&3))*8 + b.
// strip 0 = Wu (k >= 256 zero-padded).
__global__ __launch_bounds__(256) void pack_w(const float* __restrict__ Wu,
                                              const float* __restrict__ Wg,
                                              const float* __restrict__ Wa,
                                              const float* __restrict__ Wd,
                                              _Float16* __restrict__ wsB) {
  int tid = blockIdx.x * 256 + threadIdx.x;  // 65536 total
  int slot = tid & 3;
  int row = (tid >> 2) & 127;
  int cb = (tid >> 9) & 7;
  int kt = tid >> 12;  // 0..15
  int strip = (row >> 4) & 3;
  int wn = row >> 6;
  int t16 = row & 15;
  int c = cb * 32 + wn * 16 + t16;
  int k0 = kt * 32 + (slot ^ ((row >> 1) & 3)) * 8;
  float v[8];
  if (strip == 0) {
    if (k0 < 256) {
      const float* p = Wu + (size_t)c * 256 + k0;
#pragma unroll
      for (int i = 0; i < 8; ++i) v[i] = p[i];
    } else {
#pragma unroll
      for (int i = 0; i < 8; ++i) v[i] = 0.f;
    }
  } else {
    const float* p = (strip == 1 ? Wg : (strip == 2 ? Wa : Wd)) + (size_t)c * 512 + k0;
#pragma unroll
    for (int i = 0; i < 8; ++i) v[i] = p[i];
  }
  f32x4 a = {v[0], v[1], v[2], v[3]};
  f32x4 b = {v[4], v[5], v[6], v[7]};
  *reinterpret_cast<f16x8*>(wsB + (size_t)tid * 8) = cvt8(a, b);
}

// Single-barrier double-buffer pipeline (race-corrected: stage AFTER barrier).
// Block: 64 rows x 128 packed cols, 4 waves (2M x 2N), BK=32, dbuf LDS 24 KB
// -> 6 blocks/CU. Per iter kt:
//   vmcnt(0) lgkmcnt(0); s_barrier   (all reads of buf^1 provably drained)
//   issue A-gloads(kt+1) + B-glds(kt+1) into buf^1   (safe: post-barrier)
//   compute(kt) from buf  [setprio(1) around MFMA]
//   writeA(buf^1)  (implicit vmcnt retires A gloads only; B glds keep flying)
__global__ __launch_bounds__(256, 6) void rwa_main(
    const float* __restrict__ x, const float* __restrict__ nt_,
    const float* __restrict__ dt_, const float* __restrict__ h,
    const float* __restrict__ amax_, const float* __restrict__ bu,
    const float* __restrict__ bg, const _Float16* __restrict__ wsB,
    float* __restrict__ out) {
  __shared__ __align__(16) _Float16 ldsA[2][64 * 32];   // 2 x 4 KB
  __shared__ __align__(16) _Float16 ldsB[2][128 * 32];  // 2 x 8 KB

  const int tid = threadIdx.x;
  const int lane = tid & 63;
  const int l15 = lane & 15;
  const int lg = lane >> 4;
  const int wv = tid >> 6;
  const int wm = wv & 1;   // wave row-half (32 rows)
  const int wn = wv >> 1;  // wave packed-col half (64)

  // XCD swizzle: 8 cb-blocks of one rowblk share an XCD -> A panel + weights L2-hot.
  const int bid = blockIdx.x;
  const int xcd = bid & 7;
  const int q = bid >> 3;
  const int cb = q & 7;
  const int rowblk = xcd * 32 + (q >> 3);
  const int row0 = rowblk * 64;

  // A staging: thread stages row ar (0..63), 8-float chunk aq (0..3).
  const int ar = tid >> 2;
  const int aq = tid & 3;
  const int awoff = ar * 64 + ((aq ^ ((ar >> 1) & 3)) << 4);  // swizzled byte off

  // B staging source (R14 layout): per (kt,cb) slab 8 KB; thread t copies 16 B.
  const _Float16* bsrc0 = wsB + (size_t)cb * 4096 + (size_t)tid * 8;

  f32x4 acc[2][4] = {};  // [mi][strip]
  f32x4 a0, a1;          // in-flight A staging regs (next tile)

  auto issueA = [&](int kt) {
    const float* sp = (kt < 8 ? x : h) + (size_t)(row0 + ar) * 256 + (kt & 7) * 32 + aq * 8;
    a0 = *reinterpret_cast<const f32x4*>(sp);
    a1 = *reinterpret_cast<const f32x4*>(sp + 4);
  };
  auto issueB = [&](int buf, int kt) {
#pragma unroll
    for (int i = 0; i < 2; ++i) {
      __builtin_amdgcn_global_load_lds(
          (const __attribute__((address_space(1))) uint32_t*)(bsrc0 + (size_t)kt * 32768 + i * 2048),
          (__attribute__((address_space(3))) uint32_t*)(&ldsB[buf][0] + wv * 512 + i * 2048),
          16, 0, 0);
    }
  };
  auto writeA = [&](int buf) {
    *reinterpret_cast<f16x8*>(reinterpret_cast<char*>(&ldsA[buf][0]) + awoff) = cvt8(a0, a1);
  };

  // Prologue: tile 0 into buf 0 (A via regs->LDS, B glds pending).
  issueA(0);
  issueB(0, 0);
  writeA(0);  // compiler inserts vmcnt wait for a0/a1 only

#pragma unroll
  for (int kt = 0; kt < 16; ++kt) {
    const int buf = kt & 1;

    // Collective point: own B(kt) glds done (vmcnt 0), own ds ops drained
    // (lgkmcnt 0), then barrier -> buf is readable, buf^1 has no readers left.
    asm volatile("s_waitcnt vmcnt(0) lgkmcnt(0)" ::: "memory");
    __builtin_amdgcn_s_barrier();
    __builtin_amdgcn_sched_barrier(0);

    // Stage kt+1 into buf^1 (safe now). B glds fly until next iter's wait;
    // A gloads retire at writeA below.
    if (kt < 15) {
      issueA(kt + 1);
      issueB(buf ^ 1, kt + 1);
    }

    // Compute tile kt: one MFMA pass (k=32 = full BK), scheduler-prioritized.
    const bool doU = (kt < 8);  // Wu strip zero-padded beyond k=256
    const char* pA = reinterpret_cast<const char*>(&ldsA[buf][0]);
    const char* pB = reinterpret_cast<const char*>(&ldsB[buf][0]);
    {
      f16x8 af[2], bf[4];
#pragma unroll
      for (int mi = 0; mi < 2; ++mi) {
        const int row = wm * 32 + mi * 16 + l15;
        af[mi] = *reinterpret_cast<const f16x8*>(pA + row * 64 + ((lg ^ ((row >> 1) & 3)) << 4));
      }
#pragma unroll
      for (int s = 0; s < 4; ++s) {
        if (s == 0 && !doU) continue;
        const int pc = wn * 64 + s * 16 + l15;
        bf[s] = *reinterpret_cast<const f16x8*>(pB + pc * 64 + ((lg ^ ((pc >> 1) & 3)) << 4));
      }
      __builtin_amdgcn_s_setprio(1);
#pragma unroll
      for (int s = 0; s < 4; ++s) {
        if (s == 0 && !doU) continue;
#pragma unroll
        for (int mi = 0; mi < 2; ++mi)
          acc[mi][s] = __builtin_amdgcn_mfma_f32_16x16x32_f16(af[mi], bf[s], acc[mi][s], 0, 0, 0);
      }
      __builtin_amdgcn_s_setprio(0);
    }

    // Write A(kt+1) into buf^1: all waves passed this iter's barrier with
    // their buf^1 reads drained -> no WAR. Implicit vmcnt retires A gloads only.
    if (kt < 15) writeA(buf ^ 1);
  }

  __builtin_amdgcn_sched_barrier(0);  // keep epilogue loads below the loop

  // Epilogue: lane owns (r,c); u,g,a,dec local.
  const int c = cb * 32 + wn * 16 + l15;
  const float buv = bu[c];
  const float bgv = bg[c];
#pragma unroll
  for (int mi = 0; mi < 2; ++mi) {
#pragma unroll
    for (int rg = 0; rg < 4; ++rg) {
      const int r = row0 + wm * 32 + mi * 16 + lg * 4 + rg;
      const int idx = r * 256 + c;
      const float u = acc[mi][0][rg] + buv;
      const float gt = acc[mi][1][rg] + bgv;
      const float a = acc[mi][2][rg];
      const float dr = acc[mi][3][rg];
      const float sig = __builtin_amdgcn_rcpf(1.f + __expf(-dr));
      const float z = u * tanh_fast(gt);
      const float am = amax_[idx];
      const float n_old = nt_[idx];
      const float d_old = dt_[idx];
      const float e_neg = __expf(-sig);
      const float a_new = fmaxf(am * e_neg, a);
      const float comm = __expf(am - a_new - sig);  // e_neg * exp(am - a_new)
      const float escal = __expf(a - a_new);
      const float n_new = n_old * comm + z * escal;
      const float d_new = d_old * comm + escal;
      const float h_new = tanh_fast(n_new * __builtin_amdgcn_rcpf(d_new));
      out[idx] = n_new;
      out[BC + idx] = d_new;
      out[2 * BC + idx] = h_new;
      out[3 * BC + idx] = a_new;
    }
  }
}

extern "C" void kernel_launch(void* const* d_in, const int* in_sizes, int n_in,
                              void* d_out, int out_size, void* d_ws, size_t ws_size,
                              hipStream_t stream) {
  const float* x_t    = (const float*)d_in[0];
  const float* n_t    = (const float*)d_in[1];
  const float* d_t    = (const float*)d_in[2];
  const float* h_t    = (const float*)d_in[3];
  const float* amax_t = (const float*)d_in[4];
  const float* Wu     = (const float*)d_in[5];
  const float* bu     = (const float*)d_in[6];
  const float* Wg     = (const float*)d_in[7];
  const float* bg     = (const float*)d_in[8];
  const float* Wa     = (const float*)d_in[9];
  const float* Wd     = (const float*)d_in[10];
  float* out = (float*)d_out;

  _Float16* wsB = (_Float16*)d_ws;  // 1 MB packed weights (kt-outermost, BK=32)

  pack_w<<<256, 256, 0, stream>>>(Wu, Wg, Wa, Wd, wsB);
  rwa_main<<<2048, 256, 0, stream>>>(x_t, n_t, d_t, h_t, amax_t, bu, bg, wsB, out);
}